// Round 10
// baseline (127.757 us; speedup 1.0000x reference)
//
#include <hip/hip_runtime.h>

#define L_AUDIO 15360000
#define PADLEN  15361024   // 512*30000 + 1024 : exactly covers frames 0..30000
#define FRAMES  30001
#define NBAS    (1026*1024)

#define BM   256           // frames per GEMM block
#define BK   64
#define NKT  16            // 1024 / BK
#define NGEMM 472          // 118 frame-blocks x 4 channel-blocks (pairs 0..511)
#define NWG   504          // = 8 * 63 : exactly 2 rounds of 256, bijective XCD chunk

typedef __attribute__((ext_vector_type(8))) short short8;
typedef __attribute__((ext_vector_type(4))) float f32x4;

__device__ __forceinline__ unsigned short f2bf(float f) {
    unsigned int u = __float_as_uint(f);
    u += 0x7fffu + ((u >> 16) & 1u);   // round-to-nearest-even
    return (unsigned short)(u >> 16);
}

__global__ __launch_bounds__(256) void prep_pad_k(const float* __restrict__ a,
                                                  unsigned short* __restrict__ pad) {
    long i = (long)blockIdx.x * blockDim.x + threadIdx.x;   // [0, PADLEN/4)
    long p0 = i * 4;
    if (p0 >= 512 && p0 + 4 <= 512 + L_AUDIO) {
        const float4 v = *reinterpret_cast<const float4*>(a + (p0 - 512));
        ushort4 o;
        o.x = f2bf(v.x); o.y = f2bf(v.y); o.z = f2bf(v.z); o.w = f2bf(v.w);
        *reinterpret_cast<ushort4*>(pad + p0) = o;
    } else {
        for (int j = 0; j < 4; ++j) {
            long p = p0 + j;
            long src = p - 512;
            if (p < 512) src = 512 - p;
            else if (src >= L_AUDIO) src = 2L*L_AUDIO - 2 - src;
            pad[p] = f2bf(a[src]);
        }
    }
}

__global__ __launch_bounds__(256) void prep_bas_k(const float* __restrict__ b,
                                                  unsigned short* __restrict__ o) {
    long i = (long)blockIdx.x * blockDim.x + threadIdx.x;
    const float4 v = *reinterpret_cast<const float4*>(b + i * 4);
    ushort4 u;
    u.x = f2bf(v.x); u.y = f2bf(v.y); u.z = f2bf(v.z); u.w = f2bf(v.w);
    *reinterpret_cast<ushort4*>(o + i * 4) = u;
}

// GEMM blocks: 256 frames x 256 basis rows (128 pairs) x K=64 tiles, 8 waves
// (2M x 4N), per-wave 128x64. ONE __syncthreads() per tile (drains own stage
// GLDs via vmcnt(0), rendezvous, compiler memory fence). stage(t+1) issued
// immediately after the sync into the opposite buffer -> a full tile of
// compute (~5000 cyc) covers its latency before the drain at the next sync.
// Compute body is FLAT and unpinned (R9 lesson / m141: sched_barrier(0)
// order-pinning cost 60%/round; the compiler's own counted-lgkmcnt interleave
// of ds_read ahead of MFMA is near-optimal).
// Nyquist blocks (wg>=472) compute pair 512 on the VALU in fp32.
__global__ __launch_bounds__(512, 2) void stft_gemm(const unsigned short* __restrict__ pad,
                                                    const unsigned short* __restrict__ bas,
                                                    const float* __restrict__ bas32,
                                                    float* __restrict__ out) {
    __shared__ unsigned short lsA[2][BM * BK];   // 2 x 32 KB
    __shared__ unsigned short lsB[2][BM * BK];   // 2 x 32 KB

    const int tid = threadIdx.x;

    // bijective XCD-chunked remap: 504 = 8 * 63
    const int bid = blockIdx.x;
    const int wg  = (bid & 7) * 63 + (bid >> 3);

    if (wg >= NGEMM) {
        // ---- Nyquist path: out[512][f] for pair 512, fp32 VALU ----
        const int k    = wg - NGEMM;
        const int base = k * 938;                       // 32*938 >= 30001
        const int lim  = (base + 938 < FRAMES) ? base + 938 : FRAMES;
        const float* br = bas32 + (long)512  * 1024;
        const float* bi = bas32 + (long)1025 * 1024;
        float* o512 = out + (long)512 * FRAMES;
        #pragma unroll
        for (int rep = 0; rep < 2; ++rep) {
            const int f = base + rep * 512 + tid;
            if (f < lim) {
                const unsigned short* ap = pad + (long)f * 512;
                float re = 0.f, im = 0.f;
                for (int n = 0; n < 1024; n += 8) {
                    short8 a8 = *reinterpret_cast<const short8*>(ap + n);
                    #pragma unroll
                    for (int u = 0; u < 8; ++u) {
                        float av = __uint_as_float(((unsigned)(unsigned short)a8[u]) << 16);
                        re = fmaf(av, br[n + u], re);
                        im = fmaf(av, bi[n + u], im);
                    }
                }
                o512[f] = re * re + im * im;
            }
        }
        return;
    }

    const int w    = tid >> 6;
    const int lane = tid & 63;
    const int l15  = lane & 15;
    const int lk   = lane >> 4;
    const int wm   = w >> 2;          // 0..1 (M half)
    const int wn   = w & 3;           // 0..3 (N quarter)

    const int  fb = wg >> 2;          // 0..117
    const int  cb = wg & 3;           // 0..3
    const long t0 = (long)fb * BM;
    const int  c0 = cb * 128;

    // Staging sources. chunk c = j*512 + tid: row = j*64 + (tid>>3),
    // source-chunk sc = (tid&7) ^ ((tid>>3)&7)  (j-independent).
    const int sc = (tid & 7) ^ ((tid >> 3) & 7);
    const unsigned short* aS[4];
    #pragma unroll
    for (int j = 0; j < 4; ++j) {
        long tf = t0 + j * 64 + (tid >> 3);
        if (tf > FRAMES - 1) tf = FRAMES - 1;           // only fb=117 clamps
        aS[j] = pad + tf * 512 + sc * 8;
    }
    // B: brow(j) = brow0 + j*32; brow0 = ch0 + (parity? 513:0),
    // ch0 = c0 + (tid>>8)*16 + ((tid>>3)&15), parity = (tid>>7)&1.
    // (verified: LDS row j*64+r3 -> n-frag g=j*4+(r3>>4) -> channel
    //  c0 + j*32 + (r3>>5)*16 + (r3&15), imag = (r3>>4)&1 — matches read map)
    const int ch0 = c0 + ((tid >> 8) << 4) + ((tid >> 3) & 15);
    const long brow0 = ch0 + (((tid >> 7) & 1) ? 513 : 0);
    const unsigned short* bS0 = bas + brow0 * 1024 + sc * 8;

    f32x4 acc[8][4];
    #pragma unroll
    for (int a = 0; a < 8; ++a)
        #pragma unroll
        for (int b = 0; b < 4; ++b)
            acc[a][b] = (f32x4){0.f, 0.f, 0.f, 0.f};

    const int wmBase = wm * 128;
    const int wnBase = wn * 64;

#define GLD(dst, src) __builtin_amdgcn_global_load_lds( \
        (const __attribute__((address_space(1))) unsigned int*)(src), \
        (__attribute__((address_space(3))) unsigned int*)(dst), 16, 0, 0)

#define LDSREAD(basePtr, r, S) \
    (*reinterpret_cast<const short8*>(reinterpret_cast<const char*>(basePtr) \
        + (r) * 128 + ((((S) * 4 + lk) ^ ((r) & 7)) << 4)))

    // Prologue: stage tile 0 into buf 0.
    #pragma unroll
    for (int j = 0; j < 4; ++j) {
        GLD(&lsA[0][j * 4096 + tid * 8], aS[j]);
        GLD(&lsB[0][j * 4096 + tid * 8], bS0 + j * 32768);
    }

    for (int t = 0; t < NKT; ++t) {
        const int p = t & 1;
        const unsigned short* curA = lsA[p];
        const unsigned short* curB = lsB[p];

        // drains own stage(t) GLDs (vmcnt 0), syncs all waves, memory fence
        __syncthreads();

        // stage(t+1) early into the opposite buffer (safe: tile t-1's reads
        // of that buffer retired before the sync above); full tile of cover.
        if (t + 1 < NKT) {
            const int ko = (t + 1) * BK;
            unsigned short* nA = lsA[p ^ 1];
            unsigned short* nB = lsB[p ^ 1];
            #pragma unroll
            for (int j = 0; j < 4; ++j) {
                GLD(nA + j * 4096 + tid * 8, aS[j] + ko);
                GLD(nB + j * 4096 + tid * 8, bS0 + j * 32768 + ko);
            }
        }

        // Flat compute: compiler schedules ds_reads ahead of consuming MFMAs
        // with fine-grained lgkmcnt (no pins — R9/m141 lesson).
        #pragma unroll
        for (int S = 0; S < 2; ++S) {
            short8 bf[4];
            #pragma unroll
            for (int b = 0; b < 4; ++b)
                bf[b] = LDSREAD(curB, wnBase + b * 16 + l15, S);
            #pragma unroll
            for (int mq = 0; mq < 8; ++mq) {
                short8 af = LDSREAD(curA, wmBase + mq * 16 + l15, S);
                #pragma unroll
                for (int b = 0; b < 4; ++b)
                    acc[mq][b] = __builtin_amdgcn_mfma_f32_16x16x32_bf16(
                        af, bf[b], acc[mq][b], 0, 0, 0);
            }
        }
    }

    // Epilogue: out[ch][t] = re^2 + im^2 (ch = 0..511, always valid)
    const int tb = (int)t0 + wmBase;
    #pragma unroll
    for (int a = 0; a < 8; ++a) {
        #pragma unroll
        for (int q = 0; q < 2; ++q) {
            const int ch = c0 + wn * 32 + q * 16 + l15;
            const long ob = (long)ch * FRAMES;
            const int tv = tb + a * 16 + lk * 4;
            const f32x4 re = acc[a][q * 2];
            const f32x4 im = acc[a][q * 2 + 1];
            if (tv + 3 < FRAMES) {
                #pragma unroll
                for (int r = 0; r < 4; ++r)
                    out[ob + tv + r] = re[r] * re[r] + im[r] * im[r];
            } else {
                #pragma unroll
                for (int r = 0; r < 4; ++r)
                    if (tv + r < FRAMES)
                        out[ob + tv + r] = re[r] * re[r] + im[r] * im[r];
            }
        }
    }
}

extern "C" void kernel_launch(void* const* d_in, const int* in_sizes, int n_in,
                              void* d_out, int out_size, void* d_ws, size_t ws_size,
                              hipStream_t stream) {
    const float* audio = (const float*)d_in[0];
    const float* basis = (const float*)d_in[1];
    float* out = (float*)d_out;

    unsigned short* pad = (unsigned short*)d_ws;
    unsigned short* bas = pad + PADLEN;

    prep_pad_k<<<PADLEN / 4 / 256, 256, 0, stream>>>(audio, pad);
    prep_bas_k<<<NBAS / 4 / 256, 256, 0, stream>>>(basis, bas);

    stft_gemm<<<NWG, 512, 0, stream>>>(pad, bas, basis, out);
}

// Round 11
// 122.244 us; speedup vs baseline: 1.0451x; 1.0451x over previous
//
#include <hip/hip_runtime.h>

#define L_AUDIO 15360000
#define PADLEN  15361024   // 512*30000 + 1024 : exactly covers frames 0..30000
#define FRAMES  30001
#define NBAS    (1026*1024)

#define BM   256           // frames per GEMM block
#define BK   64
#define NKT  16            // 1024 / BK
#define NGEMM 472          // 118 frame-blocks x 4 channel-blocks (pairs 0..511)
#define NWG   504          // = 8 * 63 : exactly 2 rounds of 256, bijective XCD chunk

typedef __attribute__((ext_vector_type(8))) short short8;
typedef __attribute__((ext_vector_type(4))) float f32x4;

__device__ __forceinline__ unsigned short f2bf(float f) {
    unsigned int u = __float_as_uint(f);
    u += 0x7fffu + ((u >> 16) & 1u);   // round-to-nearest-even
    return (unsigned short)(u >> 16);
}

__global__ __launch_bounds__(256) void prep_pad_k(const float* __restrict__ a,
                                                  unsigned short* __restrict__ pad) {
    long i = (long)blockIdx.x * blockDim.x + threadIdx.x;   // [0, PADLEN/4)
    long p0 = i * 4;
    if (p0 >= 512 && p0 + 4 <= 512 + L_AUDIO) {
        const float4 v = *reinterpret_cast<const float4*>(a + (p0 - 512));
        ushort4 o;
        o.x = f2bf(v.x); o.y = f2bf(v.y); o.z = f2bf(v.z); o.w = f2bf(v.w);
        *reinterpret_cast<ushort4*>(pad + p0) = o;
    } else {
        for (int j = 0; j < 4; ++j) {
            long p = p0 + j;
            long src = p - 512;
            if (p < 512) src = 512 - p;
            else if (src >= L_AUDIO) src = 2L*L_AUDIO - 2 - src;
            pad[p] = f2bf(a[src]);
        }
    }
}

__global__ __launch_bounds__(256) void prep_bas_k(const float* __restrict__ b,
                                                  unsigned short* __restrict__ o) {
    long i = (long)blockIdx.x * blockDim.x + threadIdx.x;
    const float4 v = *reinterpret_cast<const float4*>(b + i * 4);
    ushort4 u;
    u.x = f2bf(v.x); u.y = f2bf(v.y); u.z = f2bf(v.z); u.w = f2bf(v.w);
    *reinterpret_cast<ushort4*>(o + i * 4) = u;
}

// R11 = R4's EXACT tile-loop structure (measured 34.2 us/block) + R10's
// verified geometry (504-grid, NCB=4 no padding, Nyquist VALU blocks).
// Per tile: issue 2 next-tile GLDs, counted vmcnt(2) (stage(t) landed,
// stage(t+1) in flight ACROSS the barrier), then 4 phases of
// {ds_read frag, 2 GLDs, barrier, setprio-MFMA cluster, barrier}.
// A/B isolation vs R10: only the loop structure differs; vs R4: only geometry.
__global__ __launch_bounds__(512, 2) void stft_gemm(const unsigned short* __restrict__ pad,
                                                    const unsigned short* __restrict__ bas,
                                                    const float* __restrict__ bas32,
                                                    float* __restrict__ out) {
    __shared__ unsigned short lsA[2][BM * BK];   // 2 x 32 KB
    __shared__ unsigned short lsB[2][BM * BK];   // 2 x 32 KB

    const int tid = threadIdx.x;

    // bijective XCD-chunked remap: 504 = 8 * 63
    const int bid = blockIdx.x;
    const int wg  = (bid & 7) * 63 + (bid >> 3);

    if (wg >= NGEMM) {
        // ---- Nyquist path: out[512][f] for pair 512, fp32 VALU ----
        const int k    = wg - NGEMM;
        const int base = k * 938;                       // 32*938 >= 30001
        const int lim  = (base + 938 < FRAMES) ? base + 938 : FRAMES;
        const float* br = bas32 + (long)512  * 1024;
        const float* bi = bas32 + (long)1025 * 1024;
        float* o512 = out + (long)512 * FRAMES;
        #pragma unroll
        for (int rep = 0; rep < 2; ++rep) {
            const int f = base + rep * 512 + tid;
            if (f < lim) {
                const unsigned short* ap = pad + (long)f * 512;
                float re = 0.f, im = 0.f;
                for (int n = 0; n < 1024; n += 8) {
                    short8 a8 = *reinterpret_cast<const short8*>(ap + n);
                    #pragma unroll
                    for (int u = 0; u < 8; ++u) {
                        float av = __uint_as_float(((unsigned)(unsigned short)a8[u]) << 16);
                        re = fmaf(av, br[n + u], re);
                        im = fmaf(av, bi[n + u], im);
                    }
                }
                o512[f] = re * re + im * im;
            }
        }
        return;
    }

    const int w    = tid >> 6;
    const int lane = tid & 63;
    const int l15  = lane & 15;
    const int lk   = lane >> 4;
    const int wm   = w >> 2;          // 0..1 (M half)
    const int wn   = w & 3;           // 0..3 (N quarter)

    const int  fb = wg >> 2;          // 0..117
    const int  cb = wg & 3;           // 0..3
    const long t0 = (long)fb * BM;
    const int  c0 = cb * 128;

    // Staging sources. chunk c = j*512 + tid: row = j*64 + (tid>>3),
    // source-chunk sc = (tid&7) ^ ((tid>>3)&7)  (j-independent).
    const int sc = (tid & 7) ^ ((tid >> 3) & 7);
    const unsigned short* aS[4];
    #pragma unroll
    for (int j = 0; j < 4; ++j) {
        long tf = t0 + j * 64 + (tid >> 3);
        if (tf > FRAMES - 1) tf = FRAMES - 1;           // only fb=117 clamps
        aS[j] = pad + tf * 512 + sc * 8;
    }
    // B: brow(j) = brow0 + j*32; brow0 = ch0 + (parity? 513:0),
    // ch0 = c0 + (tid>>8)*16 + ((tid>>3)&15), parity = (tid>>7)&1.
    const int ch0 = c0 + ((tid >> 8) << 4) + ((tid >> 3) & 15);
    const long brow0 = ch0 + (((tid >> 7) & 1) ? 513 : 0);
    const unsigned short* bS0 = bas + brow0 * 1024 + sc * 8;

    f32x4 acc[8][4];
    #pragma unroll
    for (int a = 0; a < 8; ++a)
        #pragma unroll
        for (int b = 0; b < 4; ++b)
            acc[a][b] = (f32x4){0.f, 0.f, 0.f, 0.f};

    const int wmBase = wm * 128;
    const int wnBase = wn * 64;

#define GLD(dst, src) __builtin_amdgcn_global_load_lds( \
        (const __attribute__((address_space(1))) unsigned int*)(src), \
        (__attribute__((address_space(3))) unsigned int*)(dst), 16, 0, 0)

#define LDSREAD(basePtr, r, S) \
    (*reinterpret_cast<const short8*>(reinterpret_cast<const char*>(basePtr) \
        + (r) * 128 + ((((S) * 4 + lk) ^ ((r) & 7)) << 4)))

#define PHASE_RA(MQ, S) do { _Pragma("unroll") \
    for (int j = 0; j < 4; ++j) { \
        const int r = wmBase + ((MQ) * 4 + j) * 16 + l15; \
        af[j] = LDSREAD(curA, r, S); } } while (0)

#define PHASE_RB(S) do { _Pragma("unroll") \
    for (int b = 0; b < 4; ++b) { \
        const int r = wnBase + b * 16 + l15; \
        bf[b] = LDSREAD(curB, r, S); } } while (0)

#define PHASE_MFMA(MQ) do { \
    __builtin_amdgcn_s_setprio(1); \
    _Pragma("unroll") for (int b_ = 0; b_ < 4; ++b_) \
      _Pragma("unroll") for (int m_ = 0; m_ < 4; ++m_) \
        acc[(MQ)*4+m_][b_] = __builtin_amdgcn_mfma_f32_16x16x32_bf16( \
            af[m_], bf[b_], acc[(MQ)*4+m_][b_], 0, 0, 0); \
    __builtin_amdgcn_s_setprio(0); } while (0)

    // Prologue: stage tile 0 fully into buf 0.
    #pragma unroll
    for (int j = 0; j < 4; ++j) {
        GLD(&lsA[0][j * 4096 + tid * 8], aS[j]);
        GLD(&lsB[0][j * 4096 + tid * 8], bS0 + j * 32768);
    }

    short8 af[4], bf[4];

    for (int t = 0; t < NKT; ++t) {
        const int p = t & 1;
        const unsigned short* curA = lsA[p];
        const unsigned short* curB = lsB[p];
        unsigned short* nxtA = lsA[p ^ 1];
        unsigned short* nxtB = lsB[p ^ 1];
        const bool more = (t + 1 < NKT);
        const int ko = (t + 1) * BK;

        // next-tile A-half0 issued BEFORE the counted wait (keeps vmcnt > 0)
        if (more) { GLD(nxtA + 0 * 4096 + tid * 8, aS[0] + ko);
                    GLD(nxtA + 1 * 4096 + tid * 8, aS[1] + ko); }
        if (more) asm volatile("s_waitcnt vmcnt(2)" ::: "memory");
        else      asm volatile("s_waitcnt vmcnt(0)" ::: "memory");
        __builtin_amdgcn_s_barrier();

        // phase 1: A(mq0,S0) + B(S0)
        PHASE_RA(0, 0); PHASE_RB(0);
        if (more) { GLD(nxtA + 2 * 4096 + tid * 8, aS[2] + ko);
                    GLD(nxtA + 3 * 4096 + tid * 8, aS[3] + ko); }
        __builtin_amdgcn_s_barrier();
        PHASE_MFMA(0);
        __builtin_amdgcn_s_barrier();

        // phase 2: A(mq1,S0), B reused
        PHASE_RA(1, 0);
        if (more) { GLD(nxtB + 0 * 4096 + tid * 8, bS0 + 0 * 32768 + ko);
                    GLD(nxtB + 1 * 4096 + tid * 8, bS0 + 1 * 32768 + ko); }
        __builtin_amdgcn_s_barrier();
        PHASE_MFMA(1);
        __builtin_amdgcn_s_barrier();

        // phase 3: A(mq0,S1) + B(S1)
        PHASE_RA(0, 1); PHASE_RB(1);
        if (more) { GLD(nxtB + 2 * 4096 + tid * 8, bS0 + 2 * 32768 + ko);
                    GLD(nxtB + 3 * 4096 + tid * 8, bS0 + 3 * 32768 + ko); }
        __builtin_amdgcn_s_barrier();
        PHASE_MFMA(0);
        __builtin_amdgcn_s_barrier();

        // phase 4: A(mq1,S1)
        PHASE_RA(1, 1);
        __builtin_amdgcn_s_barrier();
        PHASE_MFMA(1);
        __builtin_amdgcn_s_barrier();
    }

    // Epilogue: out[ch][t] = re^2 + im^2 (ch = 0..511, always valid)
    const int tb = (int)t0 + wmBase;
    #pragma unroll
    for (int a = 0; a < 8; ++a) {
        #pragma unroll
        for (int q = 0; q < 2; ++q) {
            const int ch = c0 + wn * 32 + q * 16 + l15;
            const long ob = (long)ch * FRAMES;
            const int tv = tb + a * 16 + lk * 4;
            const f32x4 re = acc[a][q * 2];
            const f32x4 im = acc[a][q * 2 + 1];
            if (tv + 3 < FRAMES) {
                #pragma unroll
                for (int r = 0; r < 4; ++r)
                    out[ob + tv + r] = re[r] * re[r] + im[r] * im[r];
            } else {
                #pragma unroll
                for (int r = 0; r < 4; ++r)
                    if (tv + r < FRAMES)
                        out[ob + tv + r] = re[r] * re[r] + im[r] * im[r];
            }
        }
    }
}

extern "C" void kernel_launch(void* const* d_in, const int* in_sizes, int n_in,
                              void* d_out, int out_size, void* d_ws, size_t ws_size,
                              hipStream_t stream) {
    const float* audio = (const float*)d_in[0];
    const float* basis = (const float*)d_in[1];
    float* out = (float*)d_out;

    unsigned short* pad = (unsigned short*)d_ws;
    unsigned short* bas = pad + PADLEN;

    prep_pad_k<<<PADLEN / 4 / 256, 256, 0, stream>>>(audio, pad);
    prep_bas_k<<<NBAS / 4 / 256, 256, 0, stream>>>(basis, bas);

    stft_gemm<<<NWG, 512, 0, stream>>>(pad, bas, basis, out);
}

// Round 12
// 115.017 us; speedup vs baseline: 1.1108x; 1.0628x over previous
//
#include <hip/hip_runtime.h>

#define L_AUDIO 15360000
#define PADLEN  15361024   // 512*30002 : blocks 0..30001 of 512 samples
#define FRAMES  30001
#define NBAS    (1026*1024)

#define BM   256           // frames per GEMM block
#define BK   64
#define NKT  16            // 1024 / BK
#define NWG  512           // 8 XCDs x 64 lids : exactly 2 rounds of 256

typedef __attribute__((ext_vector_type(8))) short short8;
typedef __attribute__((ext_vector_type(4))) float f32x4;

__device__ __forceinline__ unsigned short f2bf(float f) {
    unsigned int u = __float_as_uint(f);
    u += 0x7fffu + ((u >> 16) & 1u);   // round-to-nearest-even
    return (unsigned short)(u >> 16);
}

__global__ __launch_bounds__(256) void prep_pad_k(const float* __restrict__ a,
                                                  unsigned short* __restrict__ pad) {
    long i = (long)blockIdx.x * blockDim.x + threadIdx.x;   // [0, PADLEN/4)
    long p0 = i * 4;
    if (p0 >= 512 && p0 + 4 <= 512 + L_AUDIO) {
        const float4 v = *reinterpret_cast<const float4*>(a + (p0 - 512));
        ushort4 o;
        o.x = f2bf(v.x); o.y = f2bf(v.y); o.z = f2bf(v.z); o.w = f2bf(v.w);
        *reinterpret_cast<ushort4*>(pad + p0) = o;
    } else {
        for (int j = 0; j < 4; ++j) {
            long p = p0 + j;
            long src = p - 512;
            if (p < 512) src = 512 - p;
            else if (src >= L_AUDIO) src = 2L*L_AUDIO - 2 - src;
            pad[p] = f2bf(a[src]);
        }
    }
}

__global__ __launch_bounds__(256) void prep_bas_k(const float* __restrict__ b,
                                                  unsigned short* __restrict__ o) {
    long i = (long)blockIdx.x * blockDim.x + threadIdx.x;
    const float4 v = *reinterpret_cast<const float4*>(b + i * 4);
    ushort4 u;
    u.x = f2bf(v.x); u.y = f2bf(v.y); u.z = f2bf(v.z); u.w = f2bf(v.w);
    *reinterpret_cast<ushort4*>(o + i * 4) = u;
}

// GEMM blocks (lid 0..58 per XCD, wg 0..471): R4's exact tile-loop structure
// (counted vmcnt(2), 4 phases, setprio clusters) on the no-padding geometry.
// Nyquist blocks (lid 59..63 per XCD, 40 total, XCD-spread): pair 512 via
// hop-512 block decomposition — each 512-sample unit u gives coalesced
// partial dots p0(u) (first-half basis) and p1(u) (second-half basis);
// out[512][u-1] = (p0(u-1) + p1(u))^2. Imag row 1025 is FFT roundoff
// (~1e-13) -> contribution ~1e-23, skipped.
__global__ __launch_bounds__(512, 2) void stft_gemm(const unsigned short* __restrict__ pad,
                                                    const unsigned short* __restrict__ bas,
                                                    const float* __restrict__ bas32,
                                                    float* __restrict__ out) {
    __shared__ unsigned short lsA[2][BM * BK];   // 2 x 32 KB
    __shared__ unsigned short lsB[2][BM * BK];   // 2 x 32 KB

    const int tid  = threadIdx.x;
    const int bid  = blockIdx.x;
    const int xcd  = bid & 7;
    const int lid  = bid >> 3;          // 0..63

    const int w    = tid >> 6;
    const int lane = tid & 63;

    if (lid >= 59) {
        // ---- Nyquist path: pair 512, coalesced block-decomposed dots ----
        const int k  = xcd * 5 + (lid - 59);            // 0..39
        const int F0 = k * 751;
        const int F1 = (F0 + 751 < FRAMES) ? F0 + 751 : FRAMES;
        int a = F0 + w * 94;                            // 8 waves x 94 >= 751
        int b = a + 94; if (b > F1) b = F1;
        if (a < b) {
            const float* brA = bas32 + (long)512 * 1024 + lane * 8;
            float bA[8], bB[8];
            #pragma unroll
            for (int j = 0; j < 8; ++j) { bA[j] = brA[j]; bB[j] = brA[512 + j]; }
            float* o512 = out + (long)512 * FRAMES;
            float prev_p0 = 0.f;
            for (int u = a; u <= b; ++u) {              // unit u: pad[u*512 ..)
                short8 a8 = *reinterpret_cast<const short8*>(pad + (long)u * 512 + lane * 8);
                float p0 = 0.f, p1 = 0.f;
                #pragma unroll
                for (int j = 0; j < 8; ++j) {
                    float av = __uint_as_float(((unsigned)(unsigned short)a8[j]) << 16);
                    p0 = fmaf(av, bA[j], p0);
                    p1 = fmaf(av, bB[j], p1);
                }
                #pragma unroll
                for (int off = 32; off; off >>= 1) {
                    p0 += __shfl_xor(p0, off, 64);
                    p1 += __shfl_xor(p1, off, 64);
                }
                if (u > a && lane == 0) {
                    const float v = prev_p0 + p1;       // frame u-1
                    o512[u - 1] = v * v;
                }
                prev_p0 = p0;
            }
        }
        return;
    }

    const int wg = xcd * 59 + lid;      // 0..471, XCD-chunked (4 cbs share a fb)

    const int l15  = lane & 15;
    const int lk   = lane >> 4;
    const int wm   = w >> 2;            // 0..1 (M half)
    const int wn   = w & 3;             // 0..3 (N quarter)

    const int  fb = wg >> 2;            // 0..117
    const int  cb = wg & 3;             // 0..3
    const long t0 = (long)fb * BM;
    const int  c0 = cb * 128;

    // Staging sources. chunk c = j*512 + tid: row = j*64 + (tid>>3),
    // source-chunk sc = (tid&7) ^ ((tid>>3)&7)  (j-independent).
    const int sc = (tid & 7) ^ ((tid >> 3) & 7);
    const unsigned short* aS[4];
    #pragma unroll
    for (int j = 0; j < 4; ++j) {
        long tf = t0 + j * 64 + (tid >> 3);
        if (tf > FRAMES - 1) tf = FRAMES - 1;           // only fb=117 clamps
        aS[j] = pad + tf * 512 + sc * 8;
    }
    // B: brow(j) = brow0 + j*32; brow0 = ch0 + (parity? 513:0),
    // ch0 = c0 + (tid>>8)*16 + ((tid>>3)&15), parity = (tid>>7)&1.
    const int ch0 = c0 + ((tid >> 8) << 4) + ((tid >> 3) & 15);
    const long brow0 = ch0 + (((tid >> 7) & 1) ? 513 : 0);
    const unsigned short* bS0 = bas + brow0 * 1024 + sc * 8;

    f32x4 acc[8][4];
    #pragma unroll
    for (int a = 0; a < 8; ++a)
        #pragma unroll
        for (int b = 0; b < 4; ++b)
            acc[a][b] = (f32x4){0.f, 0.f, 0.f, 0.f};

    const int wmBase = wm * 128;
    const int wnBase = wn * 64;

#define GLD(dst, src) __builtin_amdgcn_global_load_lds( \
        (const __attribute__((address_space(1))) unsigned int*)(src), \
        (__attribute__((address_space(3))) unsigned int*)(dst), 16, 0, 0)

#define LDSREAD(basePtr, r, S) \
    (*reinterpret_cast<const short8*>(reinterpret_cast<const char*>(basePtr) \
        + (r) * 128 + ((((S) * 4 + lk) ^ ((r) & 7)) << 4)))

#define PHASE_RA(MQ, S) do { _Pragma("unroll") \
    for (int j = 0; j < 4; ++j) { \
        const int r = wmBase + ((MQ) * 4 + j) * 16 + l15; \
        af[j] = LDSREAD(curA, r, S); } } while (0)

#define PHASE_RB(S) do { _Pragma("unroll") \
    for (int b = 0; b < 4; ++b) { \
        const int r = wnBase + b * 16 + l15; \
        bf[b] = LDSREAD(curB, r, S); } } while (0)

#define PHASE_MFMA(MQ) do { \
    __builtin_amdgcn_s_setprio(1); \
    _Pragma("unroll") for (int b_ = 0; b_ < 4; ++b_) \
      _Pragma("unroll") for (int m_ = 0; m_ < 4; ++m_) \
        acc[(MQ)*4+m_][b_] = __builtin_amdgcn_mfma_f32_16x16x32_bf16( \
            af[m_], bf[b_], acc[(MQ)*4+m_][b_], 0, 0, 0); \
    __builtin_amdgcn_s_setprio(0); } while (0)

    // Prologue: stage tile 0 fully into buf 0.
    #pragma unroll
    for (int j = 0; j < 4; ++j) {
        GLD(&lsA[0][j * 4096 + tid * 8], aS[j]);
        GLD(&lsB[0][j * 4096 + tid * 8], bS0 + j * 32768);
    }

    short8 af[4], bf[4];

    for (int t = 0; t < NKT; ++t) {
        const int p = t & 1;
        const unsigned short* curA = lsA[p];
        const unsigned short* curB = lsB[p];
        unsigned short* nxtA = lsA[p ^ 1];
        unsigned short* nxtB = lsB[p ^ 1];
        const bool more = (t + 1 < NKT);
        const int ko = (t + 1) * BK;

        // next-tile A-half0 issued BEFORE the counted wait (keeps vmcnt > 0)
        if (more) { GLD(nxtA + 0 * 4096 + tid * 8, aS[0] + ko);
                    GLD(nxtA + 1 * 4096 + tid * 8, aS[1] + ko); }
        if (more) asm volatile("s_waitcnt vmcnt(2)" ::: "memory");
        else      asm volatile("s_waitcnt vmcnt(0)" ::: "memory");
        __builtin_amdgcn_s_barrier();

        // phase 1: A(mq0,S0) + B(S0)
        PHASE_RA(0, 0); PHASE_RB(0);
        if (more) { GLD(nxtA + 2 * 4096 + tid * 8, aS[2] + ko);
                    GLD(nxtA + 3 * 4096 + tid * 8, aS[3] + ko); }
        __builtin_amdgcn_s_barrier();
        PHASE_MFMA(0);
        __builtin_amdgcn_s_barrier();

        // phase 2: A(mq1,S0), B reused
        PHASE_RA(1, 0);
        if (more) { GLD(nxtB + 0 * 4096 + tid * 8, bS0 + 0 * 32768 + ko);
                    GLD(nxtB + 1 * 4096 + tid * 8, bS0 + 1 * 32768 + ko); }
        __builtin_amdgcn_s_barrier();
        PHASE_MFMA(1);
        __builtin_amdgcn_s_barrier();

        // phase 3: A(mq0,S1) + B(S1)
        PHASE_RA(0, 1); PHASE_RB(1);
        if (more) { GLD(nxtB + 2 * 4096 + tid * 8, bS0 + 2 * 32768 + ko);
                    GLD(nxtB + 3 * 4096 + tid * 8, bS0 + 3 * 32768 + ko); }
        __builtin_amdgcn_s_barrier();
        PHASE_MFMA(0);
        __builtin_amdgcn_s_barrier();

        // phase 4: A(mq1,S1)
        PHASE_RA(1, 1);
        __builtin_amdgcn_s_barrier();
        PHASE_MFMA(1);
        __builtin_amdgcn_s_barrier();
    }

    // Epilogue: out[ch][t] = re^2 + im^2 (ch = 0..511, always valid)
    const int tb = (int)t0 + wmBase;
    #pragma unroll
    for (int a = 0; a < 8; ++a) {
        #pragma unroll
        for (int q = 0; q < 2; ++q) {
            const int ch = c0 + wn * 32 + q * 16 + l15;
            const long ob = (long)ch * FRAMES;
            const int tv = tb + a * 16 + lk * 4;
            const f32x4 re = acc[a][q * 2];
            const f32x4 im = acc[a][q * 2 + 1];
            if (tv + 3 < FRAMES) {
                #pragma unroll
                for (int r = 0; r < 4; ++r)
                    out[ob + tv + r] = re[r] * re[r] + im[r] * im[r];
            } else {
                #pragma unroll
                for (int r = 0; r < 4; ++r)
                    if (tv + r < FRAMES)
                        out[ob + tv + r] = re[r] * re[r] + im[r] * im[r];
            }
        }
    }
}

extern "C" void kernel_launch(void* const* d_in, const int* in_sizes, int n_in,
                              void* d_out, int out_size, void* d_ws, size_t ws_size,
                              hipStream_t stream) {
    const float* audio = (const float*)d_in[0];
    const float* basis = (const float*)d_in[1];
    float* out = (float*)d_out;

    unsigned short* pad = (unsigned short*)d_ws;
    unsigned short* bas = pad + PADLEN;

    prep_pad_k<<<PADLEN / 4 / 256, 256, 0, stream>>>(audio, pad);
    prep_bas_k<<<NBAS / 4 / 256, 256, 0, stream>>>(basis, bas);

    stft_gemm<<<NWG, 512, 0, stream>>>(pad, bas, basis, out);
}